// Round 8
// baseline (3443.678 us; speedup 1.0000x reference)
//
#include <hip/hip_runtime.h>
#include <hip/hip_fp16.h>

#define TT 2048
#define BB 256
#define HH 64
#define II 60
#define OO 12
#define LL 3
#define MB 8              // batches per block
#define NBLK (BB / MB)    // 32 blocks

typedef _Float16 h2    __attribute__((ext_vector_type(2)));
typedef _Float16 f16x8 __attribute__((ext_vector_type(8)));
typedef float    f32x4 __attribute__((ext_vector_type(4)));

__device__ __forceinline__ float sigf(float x)   { return 1.f / (1.f + __expf(-x)); }
__device__ __forceinline__ float tanhf2(float x) { return 2.f / (1.f + __expf(-2.f * x)) - 1.f; }

// ---- pre-pass: x [B,T,60] fp32 -> xh [B,T,64] f16 (zero-padded) ----
__global__ __launch_bounds__(256)
void xcvt(const float* __restrict__ x, _Float16* __restrict__ xh) {
  long v = (long)blockIdx.x * 256 + threadIdx.x;   // over B*T*64
  int col = (int)(v & 63);
  long rowi = v >> 6;
  float f = (col < II) ? x[rowi * II + col] : 0.f;
  xh[v] = (_Float16)f;
}

// ---- fused 3-layer wavefront LSTM, MFMA per-step GEMM ----
// Block = 8 batches. 768 threads = 3 teams x 4 waves (team l = layer l).
// Per phase s (skew-1, round-4-proven): Stage A: team l combines t=s-l
// (each thread 2 (batch,unit) elems, trans pipe); barrier; Stage B: each
// wave computes its 64-gate slice gates(t+1) = [x|h] @ W via 16x
// mfma_f32_16x16x32_f16 (K=128), accumulators seeded with bias; barrier.
// Fragment maps: A lane&15=M(batch), B lane&15=N(gate), both k = kt*32 +
// (lane>>4)*8 + j  (same map on A and B => k-permutation invariant).
// C/D: col(N)=lane&15, row(M)=(lane>>4)*4+reg  [m89-verified].
// HBF rows XOR-swizzled (elem ^ (row&7)<<3) to kill 128B-stride bank
// conflicts on ds_read_b128; GB cols XOR'd by (b>>2)<<4.
__global__ __launch_bounds__(768, 1)
void lstm3_mfma(const _Float16* __restrict__ xh, _Float16* __restrict__ hs,
                const float* __restrict__ Wih0, const float* __restrict__ Whh0,
                const float* __restrict__ bih0, const float* __restrict__ bhh0,
                const float* __restrict__ Wih1, const float* __restrict__ Whh1,
                const float* __restrict__ bih1, const float* __restrict__ bhh1,
                const float* __restrict__ Wih2, const float* __restrict__ Whh2,
                const float* __restrict__ bih2, const float* __restrict__ bhh2,
                const float* __restrict__ h0, const float* __restrict__ c0,
                float* __restrict__ hn, float* __restrict__ cn) {
  const int bm   = blockIdx.x;
  const int tid  = threadIdx.x;
  const int l    = tid >> 8;        // team / layer
  const int g    = tid & 255;
  const int lane = g & 63;
  const int wv   = g >> 6;          // wave-in-team: owns gates [64wv,64wv+64)
  const int row  = lane & 15;
  const int kgrp = lane >> 4;
  const int u    = lane;            // combine unit index

  __shared__ float GB[LL][4][MB][64];                       // gate exchange (f32)
  __shared__ __align__(16) _Float16 HBF[LL][MB][64];        // h rows (swizzled)

  const float* Wih = (l == 0) ? Wih0 : (l == 1) ? Wih1 : Wih2;
  const float* Whh = (l == 0) ? Whh0 : (l == 1) ? Whh1 : Whh2;
  const float* bih = (l == 0) ? bih0 : (l == 1) ? bih1 : bih2;
  const float* bhh = (l == 0) ? bhh0 : (l == 1) ? bhh1 : bhh2;
  const int IN = (l == 0) ? II : HH;

  // ---- resident B-fragments (weights, f16) + bias ----
  f16x8 wb[4][4];                    // [nt][kt]
  float biasv[4];
#pragma unroll
  for (int nt = 0; nt < 4; nt++) {
    const int n = wv * 64 + nt * 16 + row;
    biasv[nt] = bih[n] + bhh[n];
#pragma unroll
    for (int kt = 0; kt < 4; kt++) {
      f16x8 f;
#pragma unroll
      for (int j = 0; j < 8; j++) {
        const int k = kt * 32 + kgrp * 8 + j;
        float v;
        if (k < 64) v = (k < IN) ? Wih[(size_t)n * IN + k] : 0.f;
        else        v = Whh[(size_t)n * HH + (k - 64)];
        f[j] = (_Float16)v;
      }
      wb[nt][kt] = f;
    }
  }

  // ---- state: c in regs (2 elems/thread), h seeded into HBF ----
  float creg[2];
#pragma unroll
  for (int i = 0; i < 2; i++) {
    const int b  = 2 * wv + i;
    const int bg = bm * MB + b;
    creg[i] = c0[((size_t)l * BB + bg) * HH + u];
    float hv = h0[((size_t)l * BB + bg) * HH + u];
    HBF[l][b][u ^ ((b & 7) << 3)] = (_Float16)hv;
  }
  __syncthreads();

  const _Float16* xb = xh + (size_t)(bm * MB + (row & 7)) * TT * 64 + kgrp * 8;

  auto ldx = [&](int t, int kt) -> f16x8 {
    return *(const f16x8*)(xb + (size_t)t * 64 + kt * 32);
  };
  auto ldh = [&](int lyr, int kt) -> f16x8 {
    return *(const f16x8*)(&HBF[lyr][row & 7][(kt * 32 + kgrp * 8) ^ ((row & 7) << 3)]);
  };

  auto gemm = [&](f16x8 a0, f16x8 a1, f16x8 a2, f16x8 a3) {
    f32x4 acc[4];
#pragma unroll
    for (int nt = 0; nt < 4; nt++)
      acc[nt] = (f32x4){biasv[nt], biasv[nt], biasv[nt], biasv[nt]};
#pragma unroll
    for (int nt = 0; nt < 4; nt++) {
      acc[nt] = __builtin_amdgcn_mfma_f32_16x16x32_f16(a0, wb[nt][0], acc[nt], 0, 0, 0);
      acc[nt] = __builtin_amdgcn_mfma_f32_16x16x32_f16(a1, wb[nt][1], acc[nt], 0, 0, 0);
      acc[nt] = __builtin_amdgcn_mfma_f32_16x16x32_f16(a2, wb[nt][2], acc[nt], 0, 0, 0);
      acc[nt] = __builtin_amdgcn_mfma_f32_16x16x32_f16(a3, wb[nt][3], acc[nt], 0, 0, 0);
    }
    if (kgrp < 2) {                 // rows 0..7 valid (M=8)
#pragma unroll
      for (int nt = 0; nt < 4; nt++)
#pragma unroll
        for (int r = 0; r < 4; r++)
          GB[l][wv][4 * kgrp + r][(16 * nt + row) ^ (kgrp << 4)] = acc[nt][r];
    }
  };

  // ---- prologue: team 0 computes gates_0(0); prefetch x(1), x(2) ----
  f16x8 XA[2], XB[2];
  if (l == 0) {
    gemm(ldx(0, 0), ldx(0, 1), ldh(0, 0), ldh(0, 1));
    XA[0] = ldx(1, 0); XA[1] = ldx(1, 1);
    XB[0] = ldx(2, 0); XB[1] = ldx(2, 1);
  }
  __syncthreads();

  // ---- phases: s = 0 .. TT+1 ----
  auto phase = [&](int s, f16x8 (&X)[2]) {
    const int t = s - l;

    // Stage A: combine t (all 4 waves of the team, 2 elems/thread)
    if (t >= 0 && t < TT) {
#pragma unroll
      for (int i = 0; i < 2; i++) {
        const int b   = 2 * wv + i;
        const int col = u ^ (((b >> 2) & 3) << 4);
        float gi = GB[l][0][b][col];
        float gf = GB[l][1][b][col];
        float gg = GB[l][2][b][col];
        float go = GB[l][3][b][col];
        creg[i] = sigf(gf) * creg[i] + sigf(gi) * tanhf2(gg);
        float hv = sigf(go) * tanhf2(creg[i]);
        HBF[l][b][u ^ ((b & 7) << 3)] = (_Float16)hv;
        if (l == 2) hs[((size_t)(bm * MB + b) * TT + t) * HH + u] = (_Float16)hv;
        if (t == TT - 1) {
          const int bg = bm * MB + b;
          hn[((size_t)l * BB + bg) * HH + u] = hv;
          cn[((size_t)l * BB + bg) * HH + u] = creg[i];
        }
      }
    }
    __syncthreads();   // HBF rows + GB reads settled

    // Stage B: gates(t+1) via MFMA
    const int tn = t + 1;
    if (tn >= 0 && tn < TT) {
      if (l == 0) gemm(X[0], X[1], ldh(0, 0), ldh(0, 1));
      else        gemm(ldh(l - 1, 0), ldh(l - 1, 1), ldh(l, 0), ldh(l, 1));
    }
    if (l == 0) {                    // refill: consumed 2 phases later
      const int rt = (s + 3 < TT) ? s + 3 : TT - 1;
      X[0] = ldx(rt, 0); X[1] = ldx(rt, 1);
    }
    __syncthreads();   // GB(t+1) ready
  };

  for (int s = 0; s < TT + 2; s += 2) {
    phase(s,     XA);
    phase(s + 1, XB);
  }
}

// ---- output projection: y[b,t,:] = W_out @ h_row + b_out ----
__global__ __launch_bounds__(256)
void oproj(const _Float16* __restrict__ hs,
           const float* __restrict__ Wout,
           const float* __restrict__ bout,
           float* __restrict__ y) {
  __shared__ float Wo[OO * HH];
  __shared__ float bo[OO];
  const int tid = threadIdx.x;
  for (int i = tid; i < OO * HH; i += 256) Wo[i] = Wout[i];
  if (tid < OO) bo[tid] = bout[tid];
  __syncthreads();

  const long r = (long)blockIdx.x * 256 + tid;  // r = b*T + t
  const uint4* h4 = (const uint4*)(hs + r * HH);
  float hf[HH];
#pragma unroll
  for (int jj = 0; jj < 8; jj++) {
    uint4 q = h4[jj];
    h2 p0 = __builtin_bit_cast(h2, q.x), p1 = __builtin_bit_cast(h2, q.y);
    h2 p2 = __builtin_bit_cast(h2, q.z), p3 = __builtin_bit_cast(h2, q.w);
    hf[8 * jj + 0] = (float)p0[0]; hf[8 * jj + 1] = (float)p0[1];
    hf[8 * jj + 2] = (float)p1[0]; hf[8 * jj + 3] = (float)p1[1];
    hf[8 * jj + 4] = (float)p2[0]; hf[8 * jj + 5] = (float)p2[1];
    hf[8 * jj + 6] = (float)p3[0]; hf[8 * jj + 7] = (float)p3[1];
  }

  float out[OO];
#pragma unroll
  for (int o = 0; o < OO; o++) {
    float a0 = bo[o], a1 = 0.f, a2 = 0.f, a3 = 0.f;
#pragma unroll
    for (int k = 0; k < HH; k += 4) {
      a0 += hf[k + 0] * Wo[o * HH + k + 0];
      a1 += hf[k + 1] * Wo[o * HH + k + 1];
      a2 += hf[k + 2] * Wo[o * HH + k + 2];
      a3 += hf[k + 3] * Wo[o * HH + k + 3];
    }
    out[o] = (a0 + a1) + (a2 + a3);
  }
  float4* yp = (float4*)(y + r * OO);
#pragma unroll
  for (int q = 0; q < 3; q++)
    yp[q] = make_float4(out[4 * q], out[4 * q + 1], out[4 * q + 2], out[4 * q + 3]);
}

extern "C" void kernel_launch(void* const* d_in, const int* in_sizes, int n_in,
                              void* d_out, int out_size, void* d_ws, size_t ws_size,
                              hipStream_t stream) {
  const float* x    = (const float*)d_in[0];
  const float* h0   = (const float*)d_in[1];
  const float* c0   = (const float*)d_in[2];
  const float* Wih0 = (const float*)d_in[3];
  const float* Whh0 = (const float*)d_in[4];
  const float* bih0 = (const float*)d_in[5];
  const float* bhh0 = (const float*)d_in[6];
  const float* Wih1 = (const float*)d_in[7];
  const float* Whh1 = (const float*)d_in[8];
  const float* bih1 = (const float*)d_in[9];
  const float* bhh1 = (const float*)d_in[10];
  const float* Wih2 = (const float*)d_in[11];
  const float* Whh2 = (const float*)d_in[12];
  const float* bih2 = (const float*)d_in[13];
  const float* bhh2 = (const float*)d_in[14];
  const float* Wout = (const float*)d_in[15];
  const float* bout = (const float*)d_in[16];

  float* y  = (float*)d_out;
  float* hn = y + (size_t)BB * TT * OO;
  float* cn = hn + (size_t)LL * BB * HH;

  // ws: xh (f16 padded x) at 0; hs (f16 layer-2 h) at +128MiB (proven fit)
  _Float16* xh = (_Float16*)d_ws;
  _Float16* hs = (_Float16*)((char*)d_ws + (size_t)BB * TT * HH * 2 * sizeof(_Float16));

  xcvt<<<dim3(BB * TT * HH / 256), dim3(256), 0, stream>>>(x, xh);
  lstm3_mfma<<<dim3(NBLK), dim3(768), 0, stream>>>(xh, hs,
      Wih0, Whh0, bih0, bhh0, Wih1, Whh1, bih1, bhh1, Wih2, Whh2, bih2, bhh2,
      h0, c0, hn, cn);
  oproj<<<dim3(BB * TT / 256), dim3(256), 0, stream>>>(hs, Wout, bout, y);
}

// Round 9
// 2472.224 us; speedup vs baseline: 1.3929x; 1.3929x over previous
//
#include <hip/hip_runtime.h>
#include <hip/hip_fp16.h>

#define TT 2048
#define BB 256
#define HH 64
#define II 60
#define OO 12
#define LL 3

typedef _Float16 h2    __attribute__((ext_vector_type(2)));
typedef float    f32x2 __attribute__((ext_vector_type(2)));
typedef float    f32x4 __attribute__((ext_vector_type(4)));

#ifndef __has_builtin
#define __has_builtin(x) 0
#endif

// packed dual f32 FMA -> v_pk_fma_f32 (2 MACs / instruction, full precision)
__device__ __forceinline__ f32x2 pkfma(f32x2 a, f32x2 b, f32x2 c) {
#if __has_builtin(__builtin_elementwise_fma)
  return __builtin_elementwise_fma(a, b, c);
#else
  f32x2 r; r[0] = fmaf(a[0], b[0], c[0]); r[1] = fmaf(a[1], b[1], c[1]); return r;
#endif
}

__device__ __forceinline__ float sigf(float x)   { return 1.f / (1.f + __expf(-x)); }
__device__ __forceinline__ float tanhf2(float x) { return 2.f / (1.f + __expf(-2.f * x)) - 1.f; }

// 64-MAC dot against an f32 LDS row (wave-uniform address -> broadcast
// ds_read_b128, conflict-free). weights = 32 f32 pairs. 4 pk chains.
__device__ __forceinline__ float dotrow(const float* row, const f32x2* w, float acc0) {
  const f32x4* rp = (const f32x4*)row;      // 16 x ds_read_b128
  f32x2 a0 = {acc0, 0.f}, a1 = {0.f, 0.f}, a2 = {0.f, 0.f}, a3 = {0.f, 0.f};
#pragma unroll
  for (int j = 0; j < 8; j++) {
    f32x4 q0 = rp[2 * j], q1 = rp[2 * j + 1];
    a0 = pkfma(q0.lo, w[4 * j + 0], a0);
    a1 = pkfma(q0.hi, w[4 * j + 1], a1);
    a2 = pkfma(q1.lo, w[4 * j + 2], a2);
    a3 = pkfma(q1.hi, w[4 * j + 3], a3);
  }
  f32x2 s = (a0 + a1) + (a2 + a3);
  return s[0] + s[1];
}

// ---- fused 3-layer wavefront LSTM (round-7 schedule, f32 pk datapath) ----
// Block b = batch b (256 blocks = full machine). 768 threads = 3 teams x 4
// waves (team l = layer l); thread owns gate g = tid&255. Phase s: Stage A:
// wave l of team l combines t = s-l from gbuf, publishes h (f32) to
// HBF[l][s&3]; barrier; Stage B: all 4 waves compute gates(t+1) =
// bias + [x|h].W via v_pk_fma_f32 against f32-pair resident weights;
// team-0/wave-3 stages the next x row into a 4-slot LDS ring; barrier.
__global__ __launch_bounds__(768, 3)
void lstm3_fused(const float* __restrict__ x,
                 _Float16* __restrict__ hs,
                 const float* __restrict__ Wih0, const float* __restrict__ Whh0,
                 const float* __restrict__ bih0, const float* __restrict__ bhh0,
                 const float* __restrict__ Wih1, const float* __restrict__ Whh1,
                 const float* __restrict__ bih1, const float* __restrict__ bhh1,
                 const float* __restrict__ Wih2, const float* __restrict__ Whh2,
                 const float* __restrict__ bih2, const float* __restrict__ bhh2,
                 const float* __restrict__ h0, const float* __restrict__ c0,
                 float* __restrict__ hn, float* __restrict__ cn) {
  const int b    = blockIdx.x;
  const int tid  = threadIdx.x;
  const int l    = tid >> 8;
  const int g    = tid & 255;
  const int u    = g & 63;
  const int wv   = g >> 6;          // wave-in-team
  const int lane = u;
  const bool cw  = (wv == l);       // combine wave: SIMDs 0,1,2 across teams

  __shared__ float gbuf[LL][2][256];
  __shared__ __align__(16) float HBF[LL][4][HH];  // f32 h rows, 4-slot ring
  __shared__ __align__(16) float XL[4][HH];       // x rows (layer 0), 4-slot ring

  const float* Wih = (l == 0) ? Wih0 : (l == 1) ? Wih1 : Wih2;
  const float* Whh = (l == 0) ? Whh0 : (l == 1) ? Whh1 : Whh2;
  const float* bih = (l == 0) ? bih0 : (l == 1) ? bih1 : bih2;
  const float* bhh = (l == 0) ? bhh0 : (l == 1) ? bhh1 : bhh2;
  const int IN = (l == 0) ? II : HH;

  // resident weights: f32 pairs (k-pair j covers k=2j,2j+1; zero-pad k>=IN)
  f32x2 wxp[32], whp[32];
#pragma unroll
  for (int j = 0; j < 32; j++) {
    const int k0 = 2 * j, k1 = k0 + 1;
    f32x2 p;
    p[0] = (k0 < IN) ? Wih[(size_t)g * IN + k0] : 0.f;
    p[1] = (k1 < IN) ? Wih[(size_t)g * IN + k1] : 0.f;
    wxp[j] = p;
    f32x2 q; q[0] = Whh[(size_t)g * HH + k0]; q[1] = Whh[(size_t)g * HH + k1];
    whp[j] = q;
  }
  const float bias = bih[g] + bhh[g];

  float hreg = h0[(l * BB + b) * HH + u];
  float creg = c0[(l * BB + b) * HH + u];

  const float* xrow = x + (size_t)b * TT * II;
  f32x4 xbuf = {0.f, 0.f, 0.f, 0.f};

  // ---- prologue ----
  if (cw) HBF[l][(l + 3) & 3][u] = hreg;              // seed h_l(init), slot (l-1)&3
  if (l == 0 && wv == 3) {
    if (lane < 15) {                                   // stage x(0), x(1); hold x(2)
      *(f32x4*)&XL[0][lane * 4] = *(const f32x4*)(xrow + 0 * II + lane * 4);
      *(f32x4*)&XL[1][lane * 4] = *(const f32x4*)(xrow + 1 * II + lane * 4);
      xbuf = *(const f32x4*)(xrow + 2 * II + lane * 4);
    }
    if (lane >= 60) { XL[0][lane] = 0.f; XL[1][lane] = 0.f; XL[2][lane] = 0.f; XL[3][lane] = 0.f; }
  }
  __syncthreads();
  if (l == 0) {                                        // gates_0(0)
    float acc = dotrow(&XL[0][0], wxp, bias);
    acc = dotrow(&HBF[0][3][0], whp, acc);
    gbuf[0][0][g] = acc;
  }
  __syncthreads();

  // ---- phases s = 0 .. TT+1 (2 barriers each; round-7-proven ordering) ----
  for (int s = 0; s < TT + 2; s++) {
    const int t    = s - l;
    const int slot = s & 3;

    // Stage A: combine (one wave per team)
    if (cw && t >= 0 && t < TT) {
      const float* gb = &gbuf[l][s & 1][0];
      float g0 = gb[u], g1 = gb[64 + u], g2 = gb[128 + u], g3 = gb[192 + u];
      creg = sigf(g1) * creg + sigf(g0) * tanhf2(g2);
      hreg = sigf(g3) * tanhf2(creg);
      HBF[l][slot][u] = hreg;
      if (l == 2) hs[((size_t)b * TT + t) * HH + u] = (_Float16)hreg;
      if (t == TT - 1) {
        hn[(l * BB + b) * HH + u] = hreg;
        cn[(l * BB + b) * HH + u] = creg;
      }
    }
    __syncthreads();   // HBF rows for this phase ready

    // Stage B: gates(t+1) = bias + x-side + h-side (all 4 waves of the team)
    const int tn = t + 1;
    if (tn >= 0 && tn < TT) {
      float acc;
      if (l == 0) acc = dotrow(&XL[(s + 1) & 3][0], wxp, bias);
      else        acc = dotrow(&HBF[l - 1][slot][0], wxp, bias);
      acc = dotrow(&HBF[l][slot][0], whp, acc);
      gbuf[l][(s + 1) & 1][g] = acc;
    }
    // x staging ring: write x(s+2) (held in regs), issue load of x(s+3).
    // Slot (s+2)&3 was last read at phase s-2 -> >=2 barriers ago; next read
    // at phase s+1 after barrier-2(s)+barrier-1(s+1). Safe.
    if (l == 0 && wv == 3 && lane < 15) {
      *(f32x4*)&XL[(s + 2) & 3][lane * 4] = xbuf;
      int rt = s + 3; if (rt > TT - 1) rt = TT - 1;
      xbuf = *(const f32x4*)(xrow + (size_t)rt * II + lane * 4);
    }
    __syncthreads();   // gbuf(t+1) + staged x row ready
  }
}

// ---- output projection: y[b,t,:] = W_out @ h_row + b_out ----
__global__ __launch_bounds__(256)
void oproj(const _Float16* __restrict__ hs,
           const float* __restrict__ Wout,
           const float* __restrict__ bout,
           float* __restrict__ y) {
  __shared__ float Wo[OO * HH];
  __shared__ float bo[OO];
  const int tid = threadIdx.x;
  for (int i = tid; i < OO * HH; i += 256) Wo[i] = Wout[i];
  if (tid < OO) bo[tid] = bout[tid];
  __syncthreads();

  const long r = (long)blockIdx.x * 256 + tid;  // r = b*T + t
  const uint4* h4 = (const uint4*)(hs + r * HH);
  float hf[HH];
#pragma unroll
  for (int jj = 0; jj < 8; jj++) {
    uint4 q = h4[jj];
    h2 p0 = __builtin_bit_cast(h2, q.x), p1 = __builtin_bit_cast(h2, q.y);
    h2 p2 = __builtin_bit_cast(h2, q.z), p3 = __builtin_bit_cast(h2, q.w);
    hf[8 * jj + 0] = (float)p0[0]; hf[8 * jj + 1] = (float)p0[1];
    hf[8 * jj + 2] = (float)p1[0]; hf[8 * jj + 3] = (float)p1[1];
    hf[8 * jj + 4] = (float)p2[0]; hf[8 * jj + 5] = (float)p2[1];
    hf[8 * jj + 6] = (float)p3[0]; hf[8 * jj + 7] = (float)p3[1];
  }

  float out[OO];
#pragma unroll
  for (int o = 0; o < OO; o++) {
    float a0 = bo[o], a1 = 0.f, a2 = 0.f, a3 = 0.f;
#pragma unroll
    for (int k = 0; k < HH; k += 4) {
      a0 += hf[k + 0] * Wo[o * HH + k + 0];
      a1 += hf[k + 1] * Wo[o * HH + k + 1];
      a2 += hf[k + 2] * Wo[o * HH + k + 2];
      a3 += hf[k + 3] * Wo[o * HH + k + 3];
    }
    out[o] = (a0 + a1) + (a2 + a3);
  }
  float4* yp = (float4*)(y + r * OO);
#pragma unroll
  for (int q = 0; q < 3; q++)
    yp[q] = make_float4(out[4 * q], out[4 * q + 1], out[4 * q + 2], out[4 * q + 3]);
}

extern "C" void kernel_launch(void* const* d_in, const int* in_sizes, int n_in,
                              void* d_out, int out_size, void* d_ws, size_t ws_size,
                              hipStream_t stream) {
  const float* x    = (const float*)d_in[0];
  const float* h0   = (const float*)d_in[1];
  const float* c0   = (const float*)d_in[2];
  const float* Wih0 = (const float*)d_in[3];
  const float* Whh0 = (const float*)d_in[4];
  const float* bih0 = (const float*)d_in[5];
  const float* bhh0 = (const float*)d_in[6];
  const float* Wih1 = (const float*)d_in[7];
  const float* Whh1 = (const float*)d_in[8];
  const float* bih1 = (const float*)d_in[9];
  const float* bhh1 = (const float*)d_in[10];
  const float* Wih2 = (const float*)d_in[11];
  const float* Whh2 = (const float*)d_in[12];
  const float* bih2 = (const float*)d_in[13];
  const float* bhh2 = (const float*)d_in[14];
  const float* Wout = (const float*)d_in[15];
  const float* bout = (const float*)d_in[16];

  float* y  = (float*)d_out;
  float* hn = y + (size_t)BB * TT * OO;
  float* cn = hn + (size_t)LL * BB * HH;

  _Float16* hsbuf = (_Float16*)d_ws;   // [B,T,64] f16 layer-2 h

  lstm3_fused<<<dim3(BB), dim3(768), 0, stream>>>(x, hsbuf,
      Wih0, Whh0, bih0, bhh0, Wih1, Whh1, bih1, bhh1, Wih2, Whh2, bih2, bhh2,
      h0, c0, hn, cn);
  oproj<<<dim3(BB * TT / 256), dim3(256), 0, stream>>>(hsbuf, Wout, bout, y);
}

// Round 10
// 2015.464 us; speedup vs baseline: 1.7086x; 1.2266x over previous
//
#include <hip/hip_runtime.h>
#include <hip/hip_fp16.h>

#define TT 2048
#define BB 256
#define HH 64
#define II 60
#define OO 12
#define LL 3

typedef _Float16 h2 __attribute__((ext_vector_type(2)));
typedef unsigned u32x4 __attribute__((ext_vector_type(4)));

#ifndef __has_builtin
#define __has_builtin(x) 0
#endif

#if __has_builtin(__builtin_amdgcn_fdot2)
__device__ __forceinline__ float dot2(unsigned a, unsigned b, float acc) {
  return __builtin_amdgcn_fdot2(__builtin_bit_cast(h2, a), __builtin_bit_cast(h2, b), acc, false);
}
#else
// clang fuses cvt_f32_f16 + fma into v_fma_mix_f32 on CDNA
__device__ __forceinline__ float dot2(unsigned a, unsigned b, float acc) {
  h2 A = __builtin_bit_cast(h2, a), B = __builtin_bit_cast(h2, b);
  acc = fmaf((float)A[0], (float)B[0], acc);
  acc = fmaf((float)A[1], (float)B[1], acc);
  return acc;
}
#endif

__device__ __forceinline__ float sigf(float x)   { return 1.f / (1.f + __expf(-x)); }
__device__ __forceinline__ float tanhf2(float x) { return 2.f / (1.f + __expf(-2.f * x)) - 1.f; }

// 64-MAC dot against a register row (8 x u32x4 = 64 f16), 4 chains.
__device__ __forceinline__ float dotreg(const u32x4 (&P)[8], const unsigned* w, float acc) {
  float a0 = acc, a1 = 0.f, a2 = 0.f, a3 = 0.f;
#pragma unroll
  for (int j = 0; j < 8; j++) {
    a0 = dot2(P[j][0], w[4 * j + 0], a0);
    a1 = dot2(P[j][1], w[4 * j + 1], a1);
    a2 = dot2(P[j][2], w[4 * j + 2], a2);
    a3 = dot2(P[j][3], w[4 * j + 3], a3);
  }
  return (a0 + a1) + (a2 + a3);
}

// 64-MAC dot against an LDS f16 row. ROUND-10 CHANGE (the only one vs the
// round-7 PASS): read the row as 8x u32x4 (ds_read_b128, wave-uniform
// address -> broadcast) instead of 32x scalar unsigned (ds_read_b32).
// Same addresses, same k-pair mapping, 4x fewer LDS instructions.
__device__ __forceinline__ float dotlds(const _Float16* row, const unsigned* w, float acc) {
  const u32x4* rp = (const u32x4*)row;
  float a0 = acc, a1 = 0.f, a2 = 0.f, a3 = 0.f;
#pragma unroll
  for (int j = 0; j < 8; j++) {
    u32x4 q = rp[j];
    a0 = dot2(q[0], w[4 * j + 0], a0);
    a1 = dot2(q[1], w[4 * j + 1], a1);
    a2 = dot2(q[2], w[4 * j + 2], a2);
    a3 = dot2(q[3], w[4 * j + 3], a3);
  }
  return (a0 + a1) + (a2 + a3);
}

// ---- pre-pass: x [B,T,60] fp32 -> xh [B,T,64] f16 (zero-padded) ----
__global__ __launch_bounds__(256)
void xcvt(const float* __restrict__ x, unsigned* __restrict__ xh) {
  long v = (long)blockIdx.x * 256 + threadIdx.x;   // half2 units (B*T*32)
  int  c2 = (int)(v & 31);
  long row = v >> 5;
  int k0 = 2 * c2, k1 = k0 + 1;
  const float* xr = x + row * II;
  float f0 = (k0 < II) ? xr[k0] : 0.f;
  float f1 = (k1 < II) ? xr[k1] : 0.f;
  h2 p; p[0] = (_Float16)f0; p[1] = (_Float16)f1;
  xh[v] = __builtin_bit_cast(unsigned, p);
}

// ---- fused 3-layer wavefront LSTM (round-4/7 schedule, proven) ----
// Block b = batch b. 768 threads = 3 teams x 256 (team l = layer l).
// Phase s: team l (A) wave l combines t=s-l from gbuf, publishes h to
// hbf[l][s&3]; (B) all 4 waves compute gates(t+1). 2 barriers/phase.
__global__ __launch_bounds__(768) __attribute__((amdgpu_waves_per_eu(3, 3)))
void lstm3_fused(const unsigned* __restrict__ xh,
                 _Float16* __restrict__ hs,
                 const float* __restrict__ Wih0, const float* __restrict__ Whh0,
                 const float* __restrict__ bih0, const float* __restrict__ bhh0,
                 const float* __restrict__ Wih1, const float* __restrict__ Whh1,
                 const float* __restrict__ bih1, const float* __restrict__ bhh1,
                 const float* __restrict__ Wih2, const float* __restrict__ Whh2,
                 const float* __restrict__ bih2, const float* __restrict__ bhh2,
                 const float* __restrict__ h0, const float* __restrict__ c0,
                 float* __restrict__ hn, float* __restrict__ cn) {
  const int b   = blockIdx.x;
  const int tid = threadIdx.x;
  const int l   = tid >> 8;
  const int g   = tid & 255;
  const int u   = g & 63;
  const int w   = g >> 6;          // wave-in-team
  const bool cw = (w == l);        // combine wave: SIMDs 0,1,2 across teams

  __shared__ float gbuf[LL][2][256];
  __shared__ __align__(16) _Float16 hbf[LL][4][HH];

  const float* Wih = (l == 0) ? Wih0 : (l == 1) ? Wih1 : Wih2;
  const float* Whh = (l == 0) ? Whh0 : (l == 1) ? Whh1 : Whh2;
  const float* bih = (l == 0) ? bih0 : (l == 1) ? bih1 : bih2;
  const float* bhh = (l == 0) ? bhh0 : (l == 1) ? bhh1 : bhh2;
  const int IN = (l == 0) ? II : HH;

  // resident weights: 64 uints (f16x2 pairs)
  unsigned wx[32], wh[32];
#pragma unroll
  for (int j = 0; j < 32; j++) {
    int k0 = 2 * j, k1 = k0 + 1;
    float f0 = (k0 < IN) ? Wih[(size_t)g * IN + k0] : 0.f;
    float f1 = (k1 < IN) ? Wih[(size_t)g * IN + k1] : 0.f;
    h2 p; p[0] = (_Float16)f0; p[1] = (_Float16)f1;
    wx[j] = __builtin_bit_cast(unsigned, p);
    h2 q; q[0] = (_Float16)Whh[(size_t)g * HH + k0]; q[1] = (_Float16)Whh[(size_t)g * HH + k1];
    wh[j] = __builtin_bit_cast(unsigned, q);
  }
#pragma unroll
  for (int j = 0; j < 32; j++) {
    asm volatile("" : "+v"(wx[j]));
    asm volatile("" : "+v"(wh[j]));
  }
  const float bias = bih[g] + bhh[g];

  float hreg = h0[(l * BB + b) * HH + u];
  float creg = c0[(l * BB + b) * HH + u];

  const unsigned* xbase = xh + (long)b * TT * 32;

  // ---- prologue: seed h0 rows (slot (l-1)&3); team 0 computes gates_0(0) ----
  if (cw) hbf[l][(l + 3) & 3][u] = (_Float16)hreg;
  __syncthreads();

  u32x4 PA[8], PB[8];
  if (l == 0) {
    u32x4 T0[8];
    const u32x4* xr0 = (const u32x4*)(xbase + 0 * 32);
    const u32x4* xr1 = (const u32x4*)(xbase + 1 * 32);
    const u32x4* xr2 = (const u32x4*)(xbase + 2 * 32);
#pragma unroll
    for (int j = 0; j < 8; j++) { T0[j] = xr0[j]; PA[j] = xr1[j]; PB[j] = xr2[j]; }
    float acc = dotreg(T0, wx, bias);
    acc = dotlds(&hbf[0][3][0], wh, acc);
    gbuf[0][0][g] = acc;                              // gates_0(0)
  }
  __syncthreads();

  // ---- phase body (round-4/7 structure) ----
  auto phase = [&](int s, u32x4 (&cur)[8]) {
    const int t    = s - l;
    const int slot = s & 3;

    // Stage A: combine (one wave per team)
    if (cw && t >= 0 && t < TT) {
      const float* gb = &gbuf[l][s & 1][0];
      float g0 = gb[u], g1 = gb[64 + u], g2 = gb[128 + u], g3 = gb[192 + u];
      creg = sigf(g1) * creg + sigf(g0) * tanhf2(g2);
      hreg = sigf(g3) * tanhf2(creg);
      hbf[l][slot][u] = (_Float16)hreg;
      if (l == 2) hs[((long)b * TT + t) * HH + u] = (_Float16)hreg;
      if (t == TT - 1) {
        hn[(l * BB + b) * HH + u] = hreg;
        cn[(l * BB + b) * HH + u] = creg;
      }
    }
    __syncthreads();   // hbf rows for this phase ready

    // Stage B: gates(t+1)
    const int tn = t + 1;
    if (tn >= 0 && tn < TT) {
      float acc;
      if (l == 0) acc = dotreg(cur, wx, bias);
      else        acc = dotlds(&hbf[l - 1][slot][0], wx, bias);
      acc = dotlds(&hbf[l][slot][0], wh, acc);
      gbuf[l][(s + 1) & 1][g] = acc;
      if (l == 0 && s + 3 < TT) {                     // refill: consumed at phase s+2
        const u32x4* xr = (const u32x4*)(xbase + (long)(s + 3) * 32);
#pragma unroll
        for (int j = 0; j < 8; j++) cur[j] = xr[j];
      }
    }
    __syncthreads();   // gbuf(t+1) ready
  };

  for (int s = 0; s < TT + 2; s += 2) {
    phase(s,     PA);
    phase(s + 1, PB);
  }
}

// ---- output projection: y[b,t,:] = W_out @ h_row + b_out ----
__global__ __launch_bounds__(256)
void oproj(const _Float16* __restrict__ hs,
           const float* __restrict__ Wout,
           const float* __restrict__ bout,
           float* __restrict__ y) {
  __shared__ float Wo[OO * HH];
  __shared__ float bo[OO];
  const int tid = threadIdx.x;
  for (int i = tid; i < OO * HH; i += 256) Wo[i] = Wout[i];
  if (tid < OO) bo[tid] = bout[tid];
  __syncthreads();

  const long r = (long)blockIdx.x * 256 + tid;  // r = b*T + t
  const uint4* h4 = (const uint4*)(hs + r * HH);
  float hf[HH];
#pragma unroll
  for (int jj = 0; jj < 8; jj++) {
    uint4 q = h4[jj];
    h2 p0 = __builtin_bit_cast(h2, q.x), p1 = __builtin_bit_cast(h2, q.y);
    h2 p2 = __builtin_bit_cast(h2, q.z), p3 = __builtin_bit_cast(h2, q.w);
    hf[8 * jj + 0] = (float)p0[0]; hf[8 * jj + 1] = (float)p0[1];
    hf[8 * jj + 2] = (float)p1[0]; hf[8 * jj + 3] = (float)p1[1];
    hf[8 * jj + 4] = (float)p2[0]; hf[8 * jj + 5] = (float)p2[1];
    hf[8 * jj + 6] = (float)p3[0]; hf[8 * jj + 7] = (float)p3[1];
  }

  float out[OO];
#pragma unroll
  for (int o = 0; o < OO; o++) {
    float a0 = bo[o], a1 = 0.f, a2 = 0.f, a3 = 0.f;
#pragma unroll
    for (int k = 0; k < HH; k += 4) {
      a0 += hf[k + 0] * Wo[o * HH + k + 0];
      a1 += hf[k + 1] * Wo[o * HH + k + 1];
      a2 += hf[k + 2] * Wo[o * HH + k + 2];
      a3 += hf[k + 3] * Wo[o * HH + k + 3];
    }
    out[o] = (a0 + a1) + (a2 + a3);
  }
  float4* yp = (float4*)(y + r * OO);
#pragma unroll
  for (int q = 0; q < 3; q++)
    yp[q] = make_float4(out[4 * q], out[4 * q + 1], out[4 * q + 2], out[4 * q + 3]);
}

extern "C" void kernel_launch(void* const* d_in, const int* in_sizes, int n_in,
                              void* d_out, int out_size, void* d_ws, size_t ws_size,
                              hipStream_t stream) {
  const float* x    = (const float*)d_in[0];
  const float* h0   = (const float*)d_in[1];
  const float* c0   = (const float*)d_in[2];
  const float* Wih0 = (const float*)d_in[3];
  const float* Whh0 = (const float*)d_in[4];
  const float* bih0 = (const float*)d_in[5];
  const float* bhh0 = (const float*)d_in[6];
  const float* Wih1 = (const float*)d_in[7];
  const float* Whh1 = (const float*)d_in[8];
  const float* bih1 = (const float*)d_in[9];
  const float* bhh1 = (const float*)d_in[10];
  const float* Wih2 = (const float*)d_in[11];
  const float* Whh2 = (const float*)d_in[12];
  const float* bih2 = (const float*)d_in[13];
  const float* bhh2 = (const float*)d_in[14];
  const float* Wout = (const float*)d_in[15];
  const float* bout = (const float*)d_in[16];

  float* y  = (float*)d_out;
  float* hn = y + (size_t)BB * TT * OO;
  float* cn = hn + (size_t)LL * BB * HH;

  // ws layout (as round 7): [0, 64MiB) = xh (f16 padded x), then hs (f16 h2)
  unsigned*  xh = (unsigned*)d_ws;
  _Float16*  hs = (_Float16*)((char*)d_ws + (size_t)BB * TT * HH * 2 * sizeof(_Float16));

  xcvt<<<dim3(BB * TT * 32 / 256), dim3(256), 0, stream>>>(x, xh);
  lstm3_fused<<<dim3(BB), dim3(768), 0, stream>>>(xh, hs,
      Wih0, Whh0, bih0, bhh0, Wih1, Whh1, bih1, bhh1, Wih2, Whh2, bih2, bhh2,
      h0, c0, hn, cn);
  oproj<<<dim3(BB * TT / 256), dim3(256), 0, stream>>>(hs, Wout, bout, y);
}

// Round 11
// 1650.484 us; speedup vs baseline: 2.0865x; 1.2211x over previous
//
#include <hip/hip_runtime.h>
#include <hip/hip_fp16.h>

#define TT 2048
#define BB 256
#define HH 64
#define II 60
#define OO 12
#define LL 3

typedef _Float16 h2    __attribute__((ext_vector_type(2)));
typedef _Float16 f16x8 __attribute__((ext_vector_type(8)));
typedef float    f32x4 __attribute__((ext_vector_type(4)));

__device__ __forceinline__ float sigf(float x)   { return 1.f / (1.f + __expf(-x)); }
__device__ __forceinline__ float tanhf2(float x) { return 2.f / (1.f + __expf(-2.f * x)) - 1.f; }

// ---- pre-pass: x [B,T,60] fp32 -> xh [B,T,64] f16 (zero-padded) ----
__global__ __launch_bounds__(256)
void xcvt(const float* __restrict__ x, _Float16* __restrict__ xh) {
  long v = (long)blockIdx.x * 256 + threadIdx.x;   // over B*T*64
  int col = (int)(v & 63);
  long rowi = v >> 6;
  float f = (col < II) ? x[rowi * II + col] : 0.f;
  xh[v] = (_Float16)f;
}

// ---- fused 3-layer wavefront LSTM: round-7 schedule, MFMA Stage B ----
// Block b = batch b (256 blocks = full machine). 768 threads = 3 teams x 4
// waves (team l = layer l); wave wv owns gates [64wv, 64wv+64).
// Phase s: Stage A: wave l of team l combines t=s-l from gbuf, publishes
// h (f16) to HBF[l][s&3]; barrier; Stage B: each wave computes its 64-gate
// slice of gates(t+1) = [x|h]@W + bias as an M=1 GEMM: 16x
// mfma_f32_16x16x32_f16 (nt=4 N-slices x kt=4 K-chunks) against resident
// B-fragments; barrier. M=1: the broadcast A row makes all 16 D rows
// identical -> extraction from kgrp==0/reg0 is layout-permutation-proof.
// B map (round-8 HW-proven): lane&15=N, k = kt*32 + (lane>>4)*8 + j, same
// map used for A chunks => K-permutation invariant.
__global__ __launch_bounds__(768, 1)
void lstm3_fused(const _Float16* __restrict__ xh,
                 _Float16* __restrict__ hs,
                 const float* __restrict__ Wih0, const float* __restrict__ Whh0,
                 const float* __restrict__ bih0, const float* __restrict__ bhh0,
                 const float* __restrict__ Wih1, const float* __restrict__ Whh1,
                 const float* __restrict__ bih1, const float* __restrict__ bhh1,
                 const float* __restrict__ Wih2, const float* __restrict__ Whh2,
                 const float* __restrict__ bih2, const float* __restrict__ bhh2,
                 const float* __restrict__ h0, const float* __restrict__ c0,
                 float* __restrict__ hn, float* __restrict__ cn) {
  const int b    = blockIdx.x;
  const int tid  = threadIdx.x;
  const int l    = tid >> 8;
  const int g    = tid & 255;
  const int lane = g & 63;
  const int wv   = g >> 6;          // wave-in-team
  const int row  = lane & 15;
  const int kgrp = lane >> 4;
  const int u    = lane;
  const bool cw  = (wv == l);       // combine wave: SIMDs 0,1,2 across teams

  __shared__ float gbuf[LL][2][256];
  __shared__ __align__(16) _Float16 HBF[LL][4][HH];

  const float* Wih = (l == 0) ? Wih0 : (l == 1) ? Wih1 : Wih2;
  const float* Whh = (l == 0) ? Whh0 : (l == 1) ? Whh1 : Whh2;
  const float* bih = (l == 0) ? bih0 : (l == 1) ? bih1 : bih2;
  const float* bhh = (l == 0) ? bhh0 : (l == 1) ? bhh1 : bhh2;
  const int IN = (l == 0) ? II : HH;

  // ---- resident B-fragments (weights) + bias (round-8 proven map) ----
  f16x8 wb[4][4];                    // [nt][kt]
  float biasv[4];
#pragma unroll
  for (int nt = 0; nt < 4; nt++) {
    const int n = wv * 64 + nt * 16 + row;
    biasv[nt] = bih[n] + bhh[n];
#pragma unroll
    for (int kt = 0; kt < 4; kt++) {
      f16x8 f;
#pragma unroll
      for (int j = 0; j < 8; j++) {
        const int k = kt * 32 + kgrp * 8 + j;
        float v;
        if (k < 64) v = (k < IN) ? Wih[(size_t)n * IN + k] : 0.f;
        else        v = Whh[(size_t)n * HH + (k - 64)];
        f[j] = (_Float16)v;
      }
      wb[nt][kt] = f;
    }
  }

  float hreg = h0[(l * BB + b) * HH + u];
  float creg = c0[(l * BB + b) * HH + u];

  const _Float16* xb = xh + (size_t)b * TT * 64 + kgrp * 8;
  auto ldx = [&](int t, int c) -> f16x8 {
    return *(const f16x8*)(xb + (size_t)t * 64 + c * 32);
  };

  // M=1 GEMM: gates-slice(wv) = [a0|a1|a2|a3] @ W + bias -> gbuf[l][par]
  auto gemm = [&](f16x8 a0, f16x8 a1, f16x8 a2, f16x8 a3, int par) {
    f32x4 acc[4];
#pragma unroll
    for (int nt = 0; nt < 4; nt++)
      acc[nt] = (f32x4){biasv[nt], biasv[nt], biasv[nt], biasv[nt]};
#pragma unroll
    for (int nt = 0; nt < 4; nt++) {
      acc[nt] = __builtin_amdgcn_mfma_f32_16x16x32_f16(a0, wb[nt][0], acc[nt], 0, 0, 0);
      acc[nt] = __builtin_amdgcn_mfma_f32_16x16x32_f16(a1, wb[nt][1], acc[nt], 0, 0, 0);
      acc[nt] = __builtin_amdgcn_mfma_f32_16x16x32_f16(a2, wb[nt][2], acc[nt], 0, 0, 0);
      acc[nt] = __builtin_amdgcn_mfma_f32_16x16x32_f16(a3, wb[nt][3], acc[nt], 0, 0, 0);
    }
    if (kgrp == 0) {
#pragma unroll
      for (int nt = 0; nt < 4; nt++)
        gbuf[l][par][wv * 64 + nt * 16 + row] = acc[nt][0];
    }
  };

  // ---- prologue: seed h0 rows (slot (l-1)&3); team 0 computes gates_0(0) ----
  if (cw) HBF[l][(l + 3) & 3][u] = (_Float16)hreg;
  __syncthreads();

  f16x8 XA0, XA1, XB0, XB1;
  if (l == 0) {
    gemm(ldx(0, 0), ldx(0, 1),
         *(const f16x8*)&HBF[0][3][kgrp * 8],
         *(const f16x8*)&HBF[0][3][32 + kgrp * 8], 0);
    XA0 = ldx(1, 0); XA1 = ldx(1, 1);   // x(1): consumed at phase 0
    XB0 = ldx(2, 0); XB1 = ldx(2, 1);   // x(2): consumed at phase 1
  }
  __syncthreads();

  // ---- phase body (round-7 structure, Stage B = MFMA) ----
  auto phase = [&](int s, f16x8& X0, f16x8& X1) {
    const int t    = s - l;
    const int slot = s & 3;

    // Stage A: combine (one wave per team)
    if (cw && t >= 0 && t < TT) {
      const float* gb = &gbuf[l][s & 1][0];
      float g0 = gb[u], g1 = gb[64 + u], g2 = gb[128 + u], g3 = gb[192 + u];
      creg = sigf(g1) * creg + sigf(g0) * tanhf2(g2);
      hreg = sigf(g3) * tanhf2(creg);
      HBF[l][slot][u] = (_Float16)hreg;
      if (l == 2) hs[((size_t)b * TT + t) * HH + u] = (_Float16)hreg;
      if (t == TT - 1) {
        hn[(l * BB + b) * HH + u] = hreg;
        cn[(l * BB + b) * HH + u] = creg;
      }
    }
    __syncthreads();   // HBF rows for this phase ready

    // Stage B: gates(t+1) via MFMA
    const int tn = t + 1;
    if (tn >= 0 && tn < TT) {
      f16x8 a0, a1;
      if (l == 0) { a0 = X0; a1 = X1; }
      else {
        a0 = *(const f16x8*)&HBF[l - 1][slot][kgrp * 8];
        a1 = *(const f16x8*)&HBF[l - 1][slot][32 + kgrp * 8];
      }
      f16x8 a2 = *(const f16x8*)&HBF[l][slot][kgrp * 8];
      f16x8 a3 = *(const f16x8*)&HBF[l][slot][32 + kgrp * 8];
      gemm(a0, a1, a2, a3, (s + 1) & 1);
    }
    if (l == 0) {                      // refill: consumed at phase s+2
      int rt = s + 3; if (rt > TT - 1) rt = TT - 1;
      X0 = ldx(rt, 0); X1 = ldx(rt, 1);
    }
    __syncthreads();   // gbuf(t+1) ready
  };

  for (int s = 0; s < TT + 2; s += 2) {
    phase(s,     XA0, XA1);
    phase(s + 1, XB0, XB1);
  }
}

// ---- output projection: y[b,t,:] = W_out @ h_row + b_out ----
__global__ __launch_bounds__(256)
void oproj(const _Float16* __restrict__ hs,
           const float* __restrict__ Wout,
           const float* __restrict__ bout,
           float* __restrict__ y) {
  __shared__ float Wo[OO * HH];
  __shared__ float bo[OO];
  const int tid = threadIdx.x;
  for (int i = tid; i < OO * HH; i += 256) Wo[i] = Wout[i];
  if (tid < OO) bo[tid] = bout[tid];
  __syncthreads();

  const long r = (long)blockIdx.x * 256 + tid;  // r = b*T + t
  const uint4* h4 = (const uint4*)(hs + r * HH);
  float hf[HH];
#pragma unroll
  for (int jj = 0; jj < 8; jj++) {
    uint4 q = h4[jj];
    h2 p0 = __builtin_bit_cast(h2, q.x), p1 = __builtin_bit_cast(h2, q.y);
    h2 p2 = __builtin_bit_cast(h2, q.z), p3 = __builtin_bit_cast(h2, q.w);
    hf[8 * jj + 0] = (float)p0[0]; hf[8 * jj + 1] = (float)p0[1];
    hf[8 * jj + 2] = (float)p1[0]; hf[8 * jj + 3] = (float)p1[1];
    hf[8 * jj + 4] = (float)p2[0]; hf[8 * jj + 5] = (float)p2[1];
    hf[8 * jj + 6] = (float)p3[0]; hf[8 * jj + 7] = (float)p3[1];
  }

  float out[OO];
#pragma unroll
  for (int o = 0; o < OO; o++) {
    float a0 = bo[o], a1 = 0.f, a2 = 0.f, a3 = 0.f;
#pragma unroll
    for (int k = 0; k < HH; k += 4) {
      a0 += hf[k + 0] * Wo[o * HH + k + 0];
      a1 += hf[k + 1] * Wo[o * HH + k + 1];
      a2 += hf[k + 2] * Wo[o * HH + k + 2];
      a3 += hf[k + 3] * Wo[o * HH + k + 3];
    }
    out[o] = (a0 + a1) + (a2 + a3);
  }
  float4* yp = (float4*)(y + r * OO);
#pragma unroll
  for (int q = 0; q < 3; q++)
    yp[q] = make_float4(out[4 * q], out[4 * q + 1], out[4 * q + 2], out[4 * q + 3]);
}

extern "C" void kernel_launch(void* const* d_in, const int* in_sizes, int n_in,
                              void* d_out, int out_size, void* d_ws, size_t ws_size,
                              hipStream_t stream) {
  const float* x    = (const float*)d_in[0];
  const float* h0   = (const float*)d_in[1];
  const float* c0   = (const float*)d_in[2];
  const float* Wih0 = (const float*)d_in[3];
  const float* Whh0 = (const float*)d_in[4];
  const float* bih0 = (const float*)d_in[5];
  const float* bhh0 = (const float*)d_in[6];
  const float* Wih1 = (const float*)d_in[7];
  const float* Whh1 = (const float*)d_in[8];
  const float* bih1 = (const float*)d_in[9];
  const float* bhh1 = (const float*)d_in[10];
  const float* Wih2 = (const float*)d_in[11];
  const float* Whh2 = (const float*)d_in[12];
  const float* bih2 = (const float*)d_in[13];
  const float* bhh2 = (const float*)d_in[14];
  const float* Wout = (const float*)d_in[15];
  const float* bout = (const float*)d_in[16];

  float* y  = (float*)d_out;
  float* hn = y + (size_t)BB * TT * OO;
  float* cn = hn + (size_t)LL * BB * HH;

  // ws layout (round-7/8 proven): xh (f16 padded x) at 0; hs at +128MiB
  _Float16* xh = (_Float16*)d_ws;
  _Float16* hs = (_Float16*)((char*)d_ws + (size_t)BB * TT * HH * 2 * sizeof(_Float16));

  xcvt<<<dim3(BB * TT * HH / 256), dim3(256), 0, stream>>>(x, xh);
  lstm3_fused<<<dim3(BB), dim3(768), 0, stream>>>(xh, hs,
      Wih0, Whh0, bih0, bhh0, Wih1, Whh1, bih1, bhh1, Wih2, Whh2, bih2, bhh2,
      h0, c0, hn, cn);
  oproj<<<dim3(BB * TT / 256), dim3(256), 0, stream>>>(hs, Wout, bout, y);
}